// Round 9
// baseline (399.395 us; speedup 1.0000x reference)
//
#include <hip/hip_runtime.h>

// Problem constants (from reference)
#define B_    256
#define CIN   48
#define CBOT  8
#define H_    4096
#define SCALE_ 0.35355339059327373f   // 1/sqrt(8)

// Evidence R0-R8: dur pinned at 123-154 us across every config; all had
// exactly 16 waves/CU. Per-wave ILP null (R7, asm-enforced). Block-count at
// fixed wave-count null (R4/R8). XCD sibling-pairing halves FETCH (R8).
// fillBufferAligned (32+ waves/CU) hits 6.5 TB/s on the same chip -> read
// throughput scales with resident waves. THIS ROUND: 32 waves/CU.
//   grid 512 x 1024thr, __launch_bounds__(1024, 8) -> 2 blocks/CU (VGPR<=64).
//   Sibling pair (L, L+8) = (batch, half 0/1), same XCD (L mod 8 equal) ->
//   the duplicated x read is L2-served (R8: FETCH 196->113 MB).
//   Both siblings read the FULL batch with identical thread->column maps ->
//   gram/softmax bitwise identical, no cross-block state, replay-safe.
//   Writes: wave-uniform predicate (t>>9)==s -> each block writes only its
//   half; the other 8 waves retire early, freeing slots for the sibling.
// NT stores kept from R6 (+19%).

typedef float vf4 __attribute__((ext_vector_type(4)));

__global__ __launch_bounds__(1024, 8) void ultimus_tlp(
    const float* __restrict__ x,        // [B, 48, 4096]
    const float* __restrict__ w_down,   // [8, 48]
    const float* __restrict__ w_up,     // [48, 8]
    float* __restrict__ out)            // [B, 48, 4096] (write-only)
{
    // L in [0,512). Pair (L, L+8): same XCD, same batch, halves 0/1.
    const int L  = blockIdx.x;
    const int jj = L & 15;
    const int b  = ((L >> 4) << 3) | (jj & 7);  // batch 0..255, twice each
    const int s  = jj >> 3;                     // owned half 0/1
    const int t  = threadIdx.x;

    __shared__ float s_wdT[CIN * CBOT];   // w_down transposed: [c][o]
    __shared__ float s_red[16 * 36];      // per-wave gram partials
    __shared__ float s_am [CBOT * CBOT];  // softmaxed attention matrix
    __shared__ float s_M  [CIN * CBOT];   // M = w_up @ am, [c][j]

    if (t < CIN * CBOT) {
        const int c = t >> 3, o = t & 7;
        s_wdT[t] = w_down[o * CIN + c];
    }
    __syncthreads();

    // Full-batch coverage: thread t owns columns 4t..4t+3 (0..4095).
    const int h0 = t << 2;
    const float* xb = x + (size_t)b * (CIN * H_) + h0;

    // ---- Phase 1: kqv[o][0..3] = sum_c w_down[o][c] * x[b][c][h0..h0+3] ----
    float acc[CBOT][4];
    #pragma unroll
    for (int o = 0; o < CBOT; ++o)
        acc[o][0] = acc[o][1] = acc[o][2] = acc[o][3] = 0.0f;

    #pragma unroll 8
    for (int c = 0; c < CIN; ++c) {
        const vf4 xv = *reinterpret_cast<const vf4*>(xb + (size_t)c * H_);
        #pragma unroll
        for (int o = 0; o < CBOT; ++o) {
            const float w = s_wdT[c * CBOT + o];
            acc[o][0] += w * xv.x;
            acc[o][1] += w * xv.y;
            acc[o][2] += w * xv.z;
            acc[o][3] += w * xv.w;
        }
    }

    // ---- Phase 2: gram G[i][j] (upper triangle, 36), block-reduced ----
    // Identical thread->column map in both siblings -> bitwise-identical sums.
    float g[36];
    {
        int idx = 0;
        #pragma unroll
        for (int i = 0; i < CBOT; ++i) {
            #pragma unroll
            for (int j = i; j < CBOT; ++j, ++idx) {
                g[idx] = acc[i][0] * acc[j][0] + acc[i][1] * acc[j][1]
                       + acc[i][2] * acc[j][2] + acc[i][3] * acc[j][3];
            }
        }
    }
    #pragma unroll
    for (int k = 0; k < 36; ++k) {
        float v = g[k];
        v += __shfl_down(v, 32, 64);
        v += __shfl_down(v, 16, 64);
        v += __shfl_down(v,  8, 64);
        v += __shfl_down(v,  4, 64);
        v += __shfl_down(v,  2, 64);
        v += __shfl_down(v,  1, 64);
        g[k] = v;   // lane 0 holds wave sum
    }
    const int wave = t >> 6;
    const int lane = t & 63;
    if (lane == 0) {
        #pragma unroll
        for (int k = 0; k < 36; ++k) s_red[wave * 36 + k] = g[k];
    }
    __syncthreads();

    if (t < 36) {
        float v = 0.0f;
        #pragma unroll
        for (int w = 0; w < 16; ++w) v += s_red[w * 36 + t];
        s_red[t] = v;
    }
    __syncthreads();

    // ---- Phase 3: softmax rows (threads 0..7) ----
    if (t < 8) {
        float row[8];
        #pragma unroll
        for (int j = 0; j < 8; ++j) {
            const int i2 = t < j ? t : j;
            const int j2 = t < j ? j : t;
            const int tri = i2 * 8 - (i2 * (i2 - 1)) / 2 + (j2 - i2);
            row[j] = s_red[tri] * SCALE_;
        }
        float m = row[0];
        #pragma unroll
        for (int j = 1; j < 8; ++j) m = fmaxf(m, row[j]);
        float sum = 0.0f;
        #pragma unroll
        for (int j = 0; j < 8; ++j) { row[j] = __expf(row[j] - m); sum += row[j]; }
        const float inv = 1.0f / sum;
        #pragma unroll
        for (int j = 0; j < 8; ++j) s_am[t * 8 + j] = row[j] * inv;
    }
    __syncthreads();

    // M[c][j] = sum_o w_up[c][o] * am[o][j]  (folds both tiny matmuls)
    if (t < CIN * CBOT) {
        const int c = t >> 3, j = t & 7;
        float v = 0.0f;
        #pragma unroll
        for (int o = 0; o < CBOT; ++o)
            v += w_up[c * CBOT + o] * s_am[o * CBOT + j];
        s_M[t] = v;
    }
    __syncthreads();

    // ---- Phase 4: out[c][h0] = sum_j M[c][j] * kqv[j][h0], own half only ----
    // (t>>9)==s is wave-uniform: waves 0-7 own cols 0..2047, waves 8-15 own
    // cols 2048..4095. Non-owning waves retire, freeing slots for the sibling.
    if ((t >> 9) == s) {
        float* ob = out + (size_t)b * (CIN * H_) + h0;
        #pragma unroll 8
        for (int c = 0; c < CIN; ++c) {
            vf4 r;
            r.x = r.y = r.z = r.w = 0.0f;
            #pragma unroll
            for (int j = 0; j < CBOT; ++j) {
                const float mcj = s_M[c * CBOT + j];
                r.x += mcj * acc[j][0];
                r.y += mcj * acc[j][1];
                r.z += mcj * acc[j][2];
                r.w += mcj * acc[j][3];
            }
            __builtin_nontemporal_store(r, reinterpret_cast<vf4*>(ob + (size_t)c * H_));
        }
    }
}

extern "C" void kernel_launch(void* const* d_in, const int* in_sizes, int n_in,
                              void* d_out, int out_size, void* d_ws, size_t ws_size,
                              hipStream_t stream) {
    const float* x      = (const float*)d_in[0];
    const float* w_down = (const float*)d_in[1];
    const float* w_up   = (const float*)d_in[2];
    float* out          = (float*)d_out;

    hipLaunchKernelGGL(ultimus_tlp, dim3(2 * B_), dim3(1024), 0, stream,
                       x, w_down, w_up, out);
}